// Round 1
// baseline (243.058 us; speedup 1.0000x reference)
//
#include <hip/hip_runtime.h>
#include <math.h>

// Problem constants
#define BATCH 64
#define IN_SH 10000
#define EXP_SH 53
#define HID 1500
#define NBC 2048
#define XLD 1568          // padded leading dim for x = [h, exp_x] (1553 -> 1568)
#define KS1 32            // split-K for gemm1
#define KC1 313           // ceil(10000/32)
#define KS2 8             // split-K for gemm2
#define KC2 195           // ceil(1553/8)

#define BM 64
#define BN 64
#define BK 16

// C = A(64 x K, lda) @ B(K x N, ldb), split-K partials.
// grid.x = column tile (BN cols), grid.y = K chunk. Block = 256 threads, 4x4 micro-tile.
__global__ __launch_bounds__(256) void sgemm_part(
    const float* __restrict__ A, const float* __restrict__ Bm,
    float* __restrict__ Cpart, int N, int K, int lda, int ldb, int kchunk)
{
    __shared__ float As[BK][BM + 1];
    __shared__ float Bs[BK][BN];

    const int tid = threadIdx.x;
    const int n0 = blockIdx.x * BN;
    const int k0 = blockIdx.y * kchunk;
    const int kend = min(k0 + kchunk, K);

    const int tx = tid % 16;          // column group
    const int ty = tid / 16;          // row group
    const int mreg = ty * 4;
    const int nreg = tx * 4;

    // staging indices
    const int a_col = tid % BK;       // 0..15
    const int a_row = tid / BK;       // 0..15  (rows a_row + 16*i)
    const int b_col = tid % BN;       // 0..63
    const int b_row = tid / BN;       // 0..3   (rows b_row + 4*i)

    float acc[4][4] = {};

    for (int k = k0; k < kend; k += BK) {
        // A tile: 64 x BK
        #pragma unroll
        for (int i = 0; i < 4; i++) {
            int m  = a_row + 16 * i;
            int kk = k + a_col;
            As[a_col][m] = (kk < kend) ? A[m * lda + kk] : 0.0f;
        }
        // B tile: BK x 64
        #pragma unroll
        for (int i = 0; i < 4; i++) {
            int kk = k + b_row + 4 * i;
            int n  = n0 + b_col;
            Bs[b_row + 4 * i][b_col] = (kk < kend && n < N) ? Bm[(size_t)kk * ldb + n] : 0.0f;
        }
        __syncthreads();

        #pragma unroll
        for (int kk = 0; kk < BK; kk++) {
            float a[4], b[4];
            #pragma unroll
            for (int i = 0; i < 4; i++) a[i] = As[kk][mreg + i];
            #pragma unroll
            for (int j = 0; j < 4; j++) b[j] = Bs[kk][nreg + j];
            #pragma unroll
            for (int i = 0; i < 4; i++)
                #pragma unroll
                for (int j = 0; j < 4; j++)
                    acc[i][j] += a[i] * b[j];
        }
        __syncthreads();
    }

    float* Cp = Cpart + (size_t)blockIdx.y * (BATCH * (size_t)N);
    #pragma unroll
    for (int i = 0; i < 4; i++) {
        int m = mreg + i;
        #pragma unroll
        for (int j = 0; j < 4; j++) {
            int n = n0 + nreg + j;
            if (n < N) Cp[(size_t)m * N + n] = acc[i][j];
        }
    }
}

// Reduce gemm1 split-K partials + bias + exact GELU; also build x = [h, exp_x] padded to XLD.
__global__ __launch_bounds__(256) void combine1(
    const float* __restrict__ part, const float* __restrict__ b1,
    const float* __restrict__ expx, float* __restrict__ X)
{
    int idx = blockIdx.x * 256 + threadIdx.x;
    if (idx >= BATCH * XLD) return;
    int b = idx / XLD, n = idx % XLD;
    float v;
    if (n < HID) {
        float s = 0.0f;
        #pragma unroll
        for (int c = 0; c < KS1; c++) s += part[(size_t)c * BATCH * HID + b * HID + n];
        s += b1[n];
        v = 0.5f * s * (1.0f + erff(s * 0.70710678118654752f));  // exact erf gelu
    } else if (n < HID + EXP_SH) {
        v = expx[b * EXP_SH + (n - HID)];
    } else {
        v = 0.0f;
    }
    X[b * XLD + n] = v;
}

// Partial column-max of hpo: grid.y = row chunk (64 rows), grid.x*256 = column j.
__global__ __launch_bounds__(256) void colmax_part(
    const float* __restrict__ M, float* __restrict__ cm)
{
    int j = blockIdx.x * 256 + threadIdx.x;
    int i0 = blockIdx.y * 64;
    float m = 0.0f;  // values are in [0,1)
    #pragma unroll 8
    for (int i = i0; i < i0 + 64; i++)
        m = fmaxf(m, M[(size_t)i * NBC + j]);
    cm[blockIdx.y * NBC + j] = m;
}

// Reduce gemm2 partials + bias + sigmoid, multiply by column max, write out.
__global__ __launch_bounds__(256) void final_k(
    const float* __restrict__ part2, const float* __restrict__ b2,
    const float* __restrict__ cm, float* __restrict__ out)
{
    int j = blockIdx.x * 256 + threadIdx.x;   // 0..2047
    int b = blockIdx.y;                        // 0..63
    float s = 0.0f;
    #pragma unroll
    for (int c = 0; c < KS2; c++) s += part2[(size_t)c * BATCH * NBC + b * NBC + j];
    s += b2[j];
    float sig = 1.0f / (1.0f + expf(-s));
    float m = 0.0f;
    #pragma unroll
    for (int c = 0; c < 32; c++) m = fmaxf(m, cm[c * NBC + j]);
    out[b * NBC + j] = sig * m;
}

extern "C" void kernel_launch(void* const* d_in, const int* in_sizes, int n_in,
                              void* d_out, int out_size, void* d_ws, size_t ws_size,
                              hipStream_t stream) {
    const float* gos  = (const float*)d_in[0];
    const float* expx = (const float*)d_in[1];
    const float* W1   = (const float*)d_in[2];
    const float* b1   = (const float*)d_in[3];
    const float* W2   = (const float*)d_in[4];
    const float* b2   = (const float*)d_in[5];
    const float* hpo  = (const float*)d_in[6];
    float* out = (float*)d_out;
    float* ws  = (float*)d_ws;

    // workspace layout (floats)
    float* ws1 = ws;                                   // KS1*64*HID   = 3,072,000
    float* X   = ws1 + (size_t)KS1 * BATCH * HID;      // 64*XLD      = 100,352
    float* ws2 = X   + (size_t)BATCH * XLD;            // KS2*64*NBC  = 1,048,576
    float* cm  = ws2 + (size_t)KS2 * BATCH * NBC;      // 32*NBC      = 65,536
    // total ~17.1 MB

    // 1) GEMM1 partials: h_pre = gos @ W1
    sgemm_part<<<dim3((HID + BN - 1) / BN, KS1), 256, 0, stream>>>(
        gos, W1, ws1, HID, IN_SH, IN_SH, HID, KC1);

    // 2) column max of hpo (independent)
    colmax_part<<<dim3(NBC / 256, 32), 256, 0, stream>>>(hpo, cm);

    // 3) reduce + bias + gelu + concat exp_x -> X
    combine1<<<(BATCH * XLD + 255) / 256, 256, 0, stream>>>(ws1, b1, expx, X);

    // 4) GEMM2 partials: logits = X @ W2
    sgemm_part<<<dim3(NBC / BN, KS2), 256, 0, stream>>>(
        X, W2, ws2, NBC, HID + EXP_SH, XLD, NBC, KC2);

    // 5) reduce + bias + sigmoid + *colmax -> out
    final_k<<<dim3(NBC / 256, BATCH), 256, 0, stream>>>(ws2, b2, cm, out);
}

// Round 2
// 170.488 us; speedup vs baseline: 1.4257x; 1.4257x over previous
//
#include <hip/hip_runtime.h>
#include <math.h>

// Problem constants
#define B64 64
#define IN_SH 10000
#define GOSLD 10240         // gos bf16 padded leading dim (zero pad), mult of 32
#define EXP_SH 53
#define HID 1500
#define NPAD1 1536          // padded N for gemm1 partials
#define NBC 2048
#define K2 1553
#define XLD 1664            // X bf16 padded leading dim, covers max prefetch read
#define KS1 20              // split-K chunks gemm1
#define KCH1 512            // k per chunk (16 steps of 32)
#define KST1 16
#define KS2 13
#define KCH2 128            // 4 steps of 32
#define KST2 4

using short8  = __attribute__((ext_vector_type(8))) short;
using floatx4 = __attribute__((ext_vector_type(4))) float;
using uintx4  = __attribute__((ext_vector_type(4))) unsigned int;

__device__ __forceinline__ unsigned short f2bf(float f) {
    unsigned u = __float_as_uint(f);
    u += 0x7fffu + ((u >> 16) & 1u);   // RNE
    return (unsigned short)(u >> 16);
}

// gos fp32 [64][10000] -> bf16 [64][10240], pad zeroed
__global__ __launch_bounds__(256) void cvt_gos(const float* __restrict__ g,
                                               unsigned short* __restrict__ gb) {
    int idx = blockIdx.x * 256 + threadIdx.x;      // 64*1280 threads
    int b = idx / (GOSLD / 8);
    int k = (idx % (GOSLD / 8)) * 8;
    unsigned int o[4] = {0u, 0u, 0u, 0u};
    if (k < IN_SH) {
        const float* p = g + (size_t)b * IN_SH + k;
        #pragma unroll
        for (int i = 0; i < 4; i++) {
            float lo = p[2 * i], hi = p[2 * i + 1];
            o[i] = (unsigned)f2bf(lo) | ((unsigned)f2bf(hi) << 16);
        }
    }
    uintx4 v; v.x = o[0]; v.y = o[1]; v.z = o[2]; v.w = o[3];
    *(uintx4*)(gb + (size_t)b * GOSLD + k) = v;
}

// column max of hpo via atomicMax on uint bit pattern (all values >= 0)
__global__ __launch_bounds__(256) void colmax(const float* __restrict__ M,
                                              unsigned int* __restrict__ cmf) {
    int j  = blockIdx.x * 256 + threadIdx.x;   // 0..2047
    int i0 = blockIdx.y * 64;
    float m = 0.0f;
    #pragma unroll 16
    for (int i = i0; i < i0 + 64; i++)
        m = fmaxf(m, M[(size_t)i * NBC + j]);
    atomicMax(cmf + j, __float_as_uint(m));
}

// Direct-streaming MFMA GEMM, no LDS, no barriers.
// part[by][n][b] += sum_k W[k][n] * Bm_bf16[b][k]   (one split-K chunk per by)
// Wave w owns n-slice n0+16w..+15; 4 MFMAs/step cover all 64 batch rows.
__global__ __launch_bounds__(256) void mfma_gemm(
    const float* __restrict__ W, const unsigned short* __restrict__ Bm,
    float* __restrict__ part, int N, int Npad, int K, int ldw, int ldb,
    int kchunk, int ksteps)
{
    int tid  = threadIdx.x;
    int w    = tid >> 6;
    int lane = tid & 63;
    int q    = lane >> 4;
    int l15  = lane & 15;
    int n0   = blockIdx.x * 64;
    int k0   = blockIdx.y * kchunk;
    int cW   = n0 + 16 * w + l15;      // W column this lane reads (A-frag m index)
    bool nok = cW < N;

    floatx4 acc[4];
    #pragma unroll
    for (int s = 0; s < 4; s++) acc[s] = (floatx4){0.f, 0.f, 0.f, 0.f};

    const unsigned short* brow0 = Bm + (size_t)l15 * ldb;

    float  wv[8];
    uintx4 bv[4];
    {   // load step 0
        int kb = k0 + q * 8;
        #pragma unroll
        for (int j = 0; j < 8; j++) {
            int k = kb + j;
            wv[j] = (nok && k < K) ? W[(size_t)k * ldw + cW] : 0.f;
        }
        #pragma unroll
        for (int s = 0; s < 4; s++)
            bv[s] = *(const uintx4*)(brow0 + (size_t)s * 16 * ldb + kb);
    }

    for (int st = 0; st < ksteps; st++) {
        // prefetch next step (clamped: last iter redundantly reloads, stays in bounds)
        int stn = (st + 1 < ksteps) ? st + 1 : st;
        int kb  = k0 + stn * 32 + q * 8;
        float  wn[8];
        uintx4 bn[4];
        #pragma unroll
        for (int j = 0; j < 8; j++) {
            int k = kb + j;
            wn[j] = (nok && k < K) ? W[(size_t)k * ldw + cW] : 0.f;
        }
        #pragma unroll
        for (int s = 0; s < 4; s++)
            bn[s] = *(const uintx4*)(brow0 + (size_t)s * 16 * ldb + kb);

        // A-frag: convert this step's W column slice to bf16
        short8 af;
        #pragma unroll
        for (int j = 0; j < 8; j++) af[j] = (short)f2bf(wv[j]);
        #pragma unroll
        for (int s = 0; s < 4; s++) {
            short8 bf8 = __builtin_bit_cast(short8, bv[s]);
            acc[s] = __builtin_amdgcn_mfma_f32_16x16x32_bf16(af, bf8, acc[s], 0, 0, 0);
        }

        #pragma unroll
        for (int j = 0; j < 8; j++) wv[j] = wn[j];
        #pragma unroll
        for (int s = 0; s < 4; s++) bv[s] = bn[s];
    }

    // D lane mapping: col=lane&15 (batch within subtile), row=q*4+r (n offset)
    size_t base = (size_t)blockIdx.y * Npad * 64;
    int nrow = n0 + 16 * w + q * 4;
    #pragma unroll
    for (int s = 0; s < 4; s++) {
        #pragma unroll
        for (int r = 0; r < 4; r++)
            part[base + (size_t)(nrow + r) * 64 + s * 16 + l15] = acc[s][r];
    }
}

// reduce gemm1 partials + bias + exact GELU -> X bf16 [64][XLD] (concat exp_x, zero pad)
__global__ __launch_bounds__(256) void combine1(
    const float* __restrict__ part, const float* __restrict__ b1,
    const float* __restrict__ expx, unsigned short* __restrict__ X)
{
    int idx = blockIdx.x * 256 + threadIdx.x;   // 64*1664 threads
    int b = idx & 63;
    int n = idx >> 6;
    float v = 0.f;
    if (n < HID) {
        float s = 0.f;
        #pragma unroll
        for (int c = 0; c < KS1; c++)
            s += part[((size_t)c * NPAD1 + n) * 64 + b];
        s += b1[n];
        v = 0.5f * s * (1.0f + erff(s * 0.70710678118654752f));
    } else if (n < HID + EXP_SH) {
        v = expx[b * EXP_SH + (n - HID)];
    }
    X[(size_t)b * XLD + n] = f2bf(v);
}

// reduce gemm2 partials + bias + sigmoid, multiply by column max
__global__ __launch_bounds__(256) void final_k(
    const float* __restrict__ part2, const float* __restrict__ b2,
    const unsigned int* __restrict__ cmf, float* __restrict__ out)
{
    int idx = blockIdx.x * 256 + threadIdx.x;   // 64*2048 threads
    int b = idx & 63;
    int j = idx >> 6;
    float s = 0.f;
    #pragma unroll
    for (int c = 0; c < KS2; c++)
        s += part2[((size_t)c * NBC + j) * 64 + b];
    s += b2[j];
    float sig = 1.0f / (1.0f + expf(-s));
    out[(size_t)b * NBC + j] = sig * __uint_as_float(cmf[j]);
}

extern "C" void kernel_launch(void* const* d_in, const int* in_sizes, int n_in,
                              void* d_out, int out_size, void* d_ws, size_t ws_size,
                              hipStream_t stream) {
    const float* gos  = (const float*)d_in[0];
    const float* expx = (const float*)d_in[1];
    const float* W1   = (const float*)d_in[2];
    const float* b1   = (const float*)d_in[3];
    const float* W2   = (const float*)d_in[4];
    const float* b2   = (const float*)d_in[5];
    const float* hpo  = (const float*)d_in[6];
    float* out = (float*)d_out;

    // workspace layout (16B-aligned offsets), total 16,211,968 B
    char* ws = (char*)d_ws;
    unsigned short* gosB = (unsigned short*)ws;                          // 64*10240*2 = 1,310,720
    float* part1 = (float*)(ws + 1310720);                               // 20*1536*64*4 = 7,864,320
    unsigned short* X = (unsigned short*)(ws + 1310720 + 7864320);       // 64*1664*2 = 212,992
    float* part2 = (float*)(ws + 1310720 + 7864320 + 212992);            // 13*2048*64*4 = 6,815,744
    unsigned int* cmf = (unsigned int*)(ws + 1310720 + 7864320 + 212992 + 6815744); // 8,192

    hipMemsetAsync(cmf, 0, NBC * sizeof(unsigned int), stream);

    cvt_gos<<<(B64 * (GOSLD / 8)) / 256, 256, 0, stream>>>(gos, gosB);
    colmax<<<dim3(NBC / 256, 32), 256, 0, stream>>>(hpo, cmf);

    // GEMM1: h_pre partials = gos @ W1  (N=1500, K=10000)
    mfma_gemm<<<dim3(NPAD1 / 64, KS1), 256, 0, stream>>>(
        W1, gosB, part1, HID, NPAD1, IN_SH, HID, GOSLD, KCH1, KST1);

    combine1<<<(B64 * XLD) / 256, 256, 0, stream>>>(part1, b1, expx, X);

    // GEMM2: logit partials = X @ W2  (N=2048, K=1553)
    mfma_gemm<<<dim3(NBC / 64, KS2), 256, 0, stream>>>(
        W2, X, part2, NBC, NBC, K2, NBC, XLD, KCH2, KST2);

    final_k<<<(B64 * NBC) / 256, 256, 0, stream>>>(part2, b2, cmf, out);
}